// Round 6
// baseline (231.985 us; speedup 1.0000x reference)
//
#include <hip/hip_runtime.h>

// d_out is FLOAT32 (reference output dtype). All inputs fp32. [R5 post-mortem]

// ---------------- K1: norm_scale = cond @ w_cond.T + 1 -> ns[2][512] fp32
__global__ __launch_bounds__(256) void cond_scale_kernel(
    const float* __restrict__ cond, const float* __restrict__ w_cond, float* __restrict__ ns)
{
    int lane = threadIdx.x & 63;
    int wid = blockIdx.x * 4 + (threadIdx.x >> 6); // 0..1023
    int n = wid >> 9, c = wid & 511;
    const float* cp = cond + n * 768;
    const float* wp = w_cond + (size_t)c * 768;
    float s = 0.f;
    #pragma unroll
    for (int j = 0; j < 12; j++)
        s += cp[lane + j * 64] * wp[lane + j * 64];
    #pragma unroll
    for (int d = 1; d < 64; d <<= 1) s += __shfl_xor(s, d);
    if (lane == 0) ns[wid] = s + 1.f;
}

// ---------------- K2: inv[p] = rsqrt(mean(x[p,:]^2) + eps), one wave per token
__global__ __launch_bounds__(256) void rms_inv_kernel(
    const float* __restrict__ x, float* __restrict__ inv)
{
    int lane = threadIdx.x & 63;
    int p = blockIdx.x * 4 + (threadIdx.x >> 6); // 0..2047
    const float* xp = x + (size_t)p * 512;
    float s = 0.f;
    #pragma unroll
    for (int j = 0; j < 8; j++) { float v = xp[lane + j * 64]; s += v * v; }
    #pragma unroll
    for (int d = 1; d < 64; d <<= 1) s += __shfl_xor(s, d);
    if (lane == 0) inv[p] = rsqrtf(s * (1.f / 512.f) + 1e-6f);
}

// ---------------- K3: qkv[2048][1536] = rmsnorm(x) @ w_qkv.T  (RMS fused in A-staging)
// VALU fp32 GEMM: block 16x16 threads, tile 64x64, per-thread 4x4 microtile.
__global__ __launch_bounds__(256) void gemm_qkv(
    const float* __restrict__ x, const float* __restrict__ ns, const float* __restrict__ inv,
    const float* __restrict__ w_qkv, float* __restrict__ qkv)
{
    __shared__ __align__(16) float As[16][68];
    __shared__ __align__(16) float Bs[16][68];
    int tid = threadIdx.x;
    int tx = tid & 15, ty = tid >> 4;
    int bm = blockIdx.x * 64, bn = blockIdx.y * 64;   // bn in [0,1536)
    int lrow = tid >> 2, lc4 = (tid & 3) * 4;

    int tr = bm + lrow;               // token row for A staging
    int nb = tr >> 10;                // batch index
    float iv = inv[tr];
    const float* wrow = w_qkv + (size_t)(bn + lrow) * 512;

    float acc[4][4];
    #pragma unroll
    for (int i = 0; i < 4; i++)
    #pragma unroll
    for (int q = 0; q < 4; q++) acc[i][q] = 0.f;

    for (int k0 = 0; k0 < 512; k0 += 16) {
        float4 av = *(const float4*)(x + (size_t)tr * 512 + k0 + lc4);
        float4 nv = *(const float4*)(ns + nb * 512 + k0 + lc4);
        float4 bv = *(const float4*)(wrow + k0 + lc4);
        As[lc4 + 0][lrow] = av.x * nv.x * iv;
        As[lc4 + 1][lrow] = av.y * nv.y * iv;
        As[lc4 + 2][lrow] = av.z * nv.z * iv;
        As[lc4 + 3][lrow] = av.w * nv.w * iv;
        Bs[lc4 + 0][lrow] = bv.x; Bs[lc4 + 1][lrow] = bv.y;
        Bs[lc4 + 2][lrow] = bv.z; Bs[lc4 + 3][lrow] = bv.w;
        __syncthreads();
        #pragma unroll
        for (int kk = 0; kk < 16; kk++) {
            float4 a4 = *(const float4*)&As[kk][ty * 4];
            float4 b4 = *(const float4*)&Bs[kk][tx * 4];
            float a[4] = {a4.x, a4.y, a4.z, a4.w};
            float b[4] = {b4.x, b4.y, b4.z, b4.w};
            #pragma unroll
            for (int i = 0; i < 4; i++)
            #pragma unroll
            for (int q = 0; q < 4; q++)
                acc[i][q] += a[i] * b[q];
        }
        __syncthreads();
    }

    #pragma unroll
    for (int i = 0; i < 4; i++) {
        int row = bm + ty * 4 + i;
        #pragma unroll
        for (int q = 0; q < 4; q++)
            qkv[(size_t)row * 1536 + bn + tx * 4 + q] = acc[i][q];
    }
}

// ---------------- K4: q/k head-normalize (*sqrt(scale)) + RoPE, in-place on fp32 qkv
__global__ __launch_bounds__(256) void qknorm_rope_kernel(
    float* __restrict__ qkv, const float* __restrict__ pos, const float* __restrict__ scale)
{
    int lane = threadIdx.x & 63;
    int wid = blockIdx.x * 4 + (threadIdx.x >> 6); // qk(1)|p(11)|h(3)
    int h = wid & 7;
    int p = (wid >> 3) & 2047;
    int qk = wid >> 14;
    size_t idx = (size_t)p * 1536 + qk * 512 + h * 64 + lane;
    float v = qkv[idx];
    float ss = v * v;
    #pragma unroll
    for (int d = 1; d < 64; d <<= 1) ss += __shfl_xor(ss, d);
    float sc = sqrtf(scale[h]) * rsqrtf(ss + 1e-6f);
    v *= sc;
    float partner = __shfl_xor(v, 16);
    float res = v;
    if (lane < 32) {
        int t = lane & 15;
        // freqs[h][t] = pi * 10^((t*8+h)/128)
        float fr = 3.14159265358979323846f * expf((float)(t * 8 + h) * (2.302585092994046f / 128.f));
        float th = pos[p] * fr;
        float cs = cosf(th), sn = sinf(th);
        res = (lane < 16) ? (v * cs - partner * sn) : (v * cs + partner * sn);
    }
    qkv[idx] = res;
}

// ---------------- K5: 7x7 neighborhood attention. One wave per (token, head). fp32 out.
__global__ __launch_bounds__(256) void attn_kernel(
    const float* __restrict__ qkv, float* __restrict__ o)
{
    __shared__ float kls[4][49 * 65];  // stride 65: <=2-way bank alias (free)
    __shared__ float qls[4][64];
    __shared__ float pls[4][64];
    int w = threadIdx.x >> 6, lane = threadIdx.x & 63;
    int wid = blockIdx.x * 4 + w;  // 0..16383
    int h = wid & 7, p = wid >> 3;
    int n = p >> 10, i = (p >> 5) & 31, j = p & 31;
    int si = min(max(i - 3, 0), 25), sj = min(max(j - 3, 0), 25);

    qls[w][lane] = qkv[(size_t)p * 1536 + h * 64 + lane];
    {
        int ia = si, cj = 0;
        for (int a = 0; a < 49; a++) {
            int pp = n * 1024 + ia * 32 + (sj + cj);
            kls[w][a * 65 + lane] = qkv[(size_t)pp * 1536 + 512 + h * 64 + lane];
            if (++cj == 7) { cj = 0; ia++; }
        }
    }
    __syncthreads();

    float score = -1e30f;
    if (lane < 49) {
        float s = 0.f;
        const float* kr = &kls[w][lane * 65];
        const float* qr = qls[w];
        #pragma unroll 8
        for (int e = 0; e < 64; e++) s += qr[e] * kr[e];
        score = s;
    }
    float m = score;
    #pragma unroll
    for (int d = 1; d < 64; d <<= 1) m = fmaxf(m, __shfl_xor(m, d));
    float ex = (lane < 49) ? expf(score - m) : 0.f;
    float s = ex;
    #pragma unroll
    for (int d = 1; d < 64; d <<= 1) s += __shfl_xor(s, d);
    pls[w][lane] = ex / s;
    __syncthreads();

    float acc = 0.f;
    {
        int ia = si, cj = 0;
        for (int a = 0; a < 49; a++) {
            int pp = n * 1024 + ia * 32 + (sj + cj);
            acc += pls[w][a] * qkv[(size_t)pp * 1536 + 1024 + h * 64 + lane];
            if (++cj == 7) { cj = 0; ia++; }
        }
    }
    o[(size_t)p * 512 + h * 64 + lane] = acc;
}

// ---------------- K6: out = ob @ w_out.T + x  -> fp32 d_out
__global__ __launch_bounds__(256) void gemm_out(
    const float* __restrict__ A, const float* __restrict__ B,
    const float* __restrict__ skip, float* __restrict__ C)
{
    __shared__ __align__(16) float As[16][68];
    __shared__ __align__(16) float Bs[16][68];
    int tid = threadIdx.x;
    int tx = tid & 15, ty = tid >> 4;
    int bm = blockIdx.x * 64, bn = blockIdx.y * 64;
    int lrow = tid >> 2, lc4 = (tid & 3) * 4;

    float acc[4][4];
    #pragma unroll
    for (int i = 0; i < 4; i++)
    #pragma unroll
    for (int q = 0; q < 4; q++) acc[i][q] = 0.f;

    const float* Ap = A + (size_t)(bm + lrow) * 512 + lc4;
    const float* Bp = B + (size_t)(bn + lrow) * 512 + lc4;

    for (int k0 = 0; k0 < 512; k0 += 16) {
        float4 av = *(const float4*)(Ap + k0);
        float4 bv = *(const float4*)(Bp + k0);
        As[lc4 + 0][lrow] = av.x; As[lc4 + 1][lrow] = av.y;
        As[lc4 + 2][lrow] = av.z; As[lc4 + 3][lrow] = av.w;
        Bs[lc4 + 0][lrow] = bv.x; Bs[lc4 + 1][lrow] = bv.y;
        Bs[lc4 + 2][lrow] = bv.z; Bs[lc4 + 3][lrow] = bv.w;
        __syncthreads();
        #pragma unroll
        for (int kk = 0; kk < 16; kk++) {
            float4 a4 = *(const float4*)&As[kk][ty * 4];
            float4 b4 = *(const float4*)&Bs[kk][tx * 4];
            float a[4] = {a4.x, a4.y, a4.z, a4.w};
            float b[4] = {b4.x, b4.y, b4.z, b4.w};
            #pragma unroll
            for (int i = 0; i < 4; i++)
            #pragma unroll
            for (int q = 0; q < 4; q++)
                acc[i][q] += a[i] * b[q];
        }
        __syncthreads();
    }

    #pragma unroll
    for (int i = 0; i < 4; i++) {
        int row = bm + ty * 4 + i;
        #pragma unroll
        for (int q = 0; q < 4; q++) {
            int col = bn + tx * 4 + q;
            size_t idx = (size_t)row * 512 + col;
            C[idx] = acc[i][q] + skip[idx];
        }
    }
}

extern "C" void kernel_launch(void* const* d_in, const int* in_sizes, int n_in,
                              void* d_out, int out_size, void* d_ws, size_t ws_size,
                              hipStream_t stream)
{
    // Match inputs by unique element count (robust to ordering).
    const float *x = nullptr, *pos = nullptr, *cond = nullptr, *w_cond = nullptr,
                *w_qkv = nullptr, *scale = nullptr, *w_out = nullptr;
    for (int i = 0; i < n_in; i++) {
        switch (in_sizes[i]) {
            case 1048576: x      = (const float*)d_in[i]; break;  // 2*32*32*512
            case 2048:    pos    = (const float*)d_in[i]; break;  // 2*32*32*1
            case 1536:    cond   = (const float*)d_in[i]; break;  // 2*768
            case 393216:  w_cond = (const float*)d_in[i]; break;  // 512*768
            case 786432:  w_qkv  = (const float*)d_in[i]; break;  // 1536*512
            case 8:       scale  = (const float*)d_in[i]; break;  // 8
            case 262144:  w_out  = (const float*)d_in[i]; break;  // 512*512
            default: break;
        }
    }
    float* out = (float*)d_out;   // FLOAT32 output

    // ws: ns 4KB | inv 8KB | qkv 12MB | ob 4MB  (~16.01 MB)
    char* ws = (char*)d_ws;
    float* ns  = (float*)ws;                       // [2][512]
    float* inv = (float*)(ws + 4096);              // [2048]
    float* qkv = (float*)(ws + 12288);             // [2048][1536]
    float* ob  = (float*)(ws + 12288 + 12582912);  // [2048][512]

    cond_scale_kernel<<<256, 256, 0, stream>>>(cond, w_cond, ns);
    rms_inv_kernel<<<512, 256, 0, stream>>>(x, inv);
    gemm_qkv<<<dim3(32, 24), 256, 0, stream>>>(x, ns, inv, w_qkv, qkv);
    qknorm_rope_kernel<<<8192, 256, 0, stream>>>(qkv, pos, scale);
    attn_kernel<<<4096, 256, 0, stream>>>(qkv, ob);
    gemm_out<<<dim3(32, 8), 256, 0, stream>>>(ob, w_out, x, out);
}

// Round 7
// 172.035 us; speedup vs baseline: 1.3485x; 1.3485x over previous
//
#include <hip/hip_runtime.h>

typedef unsigned short u16;
typedef unsigned int u32;
typedef __bf16 bf16x8 __attribute__((ext_vector_type(8)));
typedef float f32x4 __attribute__((ext_vector_type(4)));

__device__ __forceinline__ float bf2f(u16 v) {
    union { u32 u; float f; } c; c.u = ((u32)v) << 16; return c.f;
}
__device__ __forceinline__ u16 f2bf(float f) {
    union { float f; u32 u; } c; c.f = f;
    u32 u = c.u + 0x7fffu + ((c.u >> 16) & 1u);   // RNE
    return (u16)(u >> 16);
}

// ---------------- K1: fused cond_scale (blocks 0..255) + rms_inv (blocks 256..767)
__global__ __launch_bounds__(256) void setup_kernel(
    const float* __restrict__ cond, const float* __restrict__ w_cond,
    const float* __restrict__ x, float* __restrict__ ns, float* __restrict__ inv)
{
    int lane = threadIdx.x & 63;
    int b = blockIdx.x;
    if (b < 256) {
        int wid = b * 4 + (threadIdx.x >> 6); // 0..1023
        int n = wid >> 9, c = wid & 511;
        const float* cp = cond + n * 768;
        const float* wp = w_cond + (size_t)c * 768;
        float s = 0.f;
        #pragma unroll
        for (int j = 0; j < 12; j++)
            s += cp[lane + j * 64] * wp[lane + j * 64];
        #pragma unroll
        for (int d = 1; d < 64; d <<= 1) s += __shfl_xor(s, d);
        if (lane == 0) ns[wid] = s + 1.f;
    } else {
        int p = (b - 256) * 4 + (threadIdx.x >> 6); // 0..2047
        const float* xp = x + (size_t)p * 512;
        float s = 0.f;
        #pragma unroll
        for (int j = 0; j < 8; j++) { float v = xp[lane + j * 64]; s += v * v; }
        #pragma unroll
        for (int d = 1; d < 64; d <<= 1) s += __shfl_xor(s, d);
        if (lane == 0) inv[p] = rsqrtf(s * (1.f / 512.f) + 1e-6f);
    }
}

// ---------------- MFMA GEMM: C[M][N] = A[M][K] @ B[N][K]^T, fp32 in (bf16-rounded
// in LDS staging), fp32 acc/out. Block tile 64x64, 4 waves 2x2, mfma 16x16x32.
// A-frag: m=lane&15, k=(lane>>4)*8+j ; C/D: col(N)=lane&15, row(M)=(lane>>4)*4+reg [m89/m91]
// SCALE_A: A row scaled by ns[batch][k] * inv[row]  (fused RMS-norm)
template<bool SCALE_A, bool ADD_SKIP>
__global__ __launch_bounds__(256) void gemm_mfma(
    const float* __restrict__ A, const float* __restrict__ ns, const float* __restrict__ inv,
    const float* __restrict__ B, float* __restrict__ C, const float* __restrict__ skip,
    int N, int K)
{
    __shared__ __align__(16) u16 As[64][40];
    __shared__ __align__(16) u16 Bs[64][40];
    int tid = threadIdx.x;
    int lane = tid & 63;
    int w = tid >> 6;
    int wm = w >> 1, wn = w & 1;
    int bm = blockIdx.x * 64, bn = blockIdx.y * 64;
    int lrow = tid >> 2, lc8 = (tid & 3) * 8;

    int tr = bm + lrow;
    float iv = 0.f; int nsoff = 0;
    if (SCALE_A) { iv = inv[tr]; nsoff = (tr >> 10) * 512; }

    const float* Ap = A + (size_t)tr * K + lc8;
    const float* Bp = B + (size_t)(bn + lrow) * K + lc8;

    f32x4 zero = {0.f, 0.f, 0.f, 0.f};
    f32x4 acc[2][2];
    acc[0][0] = zero; acc[0][1] = zero; acc[1][0] = zero; acc[1][1] = zero;
    int r = lane & 15, kq = (lane >> 4) * 8;

    for (int k0 = 0; k0 < K; k0 += 32) {
        float4 a0 = *(const float4*)(Ap + k0);
        float4 a1 = *(const float4*)(Ap + k0 + 4);
        if (SCALE_A) {
            float4 n0 = *(const float4*)(ns + nsoff + k0 + lc8);
            float4 n1 = *(const float4*)(ns + nsoff + k0 + lc8 + 4);
            a0.x *= n0.x * iv; a0.y *= n0.y * iv; a0.z *= n0.z * iv; a0.w *= n0.w * iv;
            a1.x *= n1.x * iv; a1.y *= n1.y * iv; a1.z *= n1.z * iv; a1.w *= n1.w * iv;
        }
        float4 b0 = *(const float4*)(Bp + k0);
        float4 b1 = *(const float4*)(Bp + k0 + 4);
        uint4 ap, bp;
        ap.x = (u32)f2bf(a0.x) | ((u32)f2bf(a0.y) << 16);
        ap.y = (u32)f2bf(a0.z) | ((u32)f2bf(a0.w) << 16);
        ap.z = (u32)f2bf(a1.x) | ((u32)f2bf(a1.y) << 16);
        ap.w = (u32)f2bf(a1.z) | ((u32)f2bf(a1.w) << 16);
        bp.x = (u32)f2bf(b0.x) | ((u32)f2bf(b0.y) << 16);
        bp.y = (u32)f2bf(b0.z) | ((u32)f2bf(b0.w) << 16);
        bp.z = (u32)f2bf(b1.x) | ((u32)f2bf(b1.y) << 16);
        bp.w = (u32)f2bf(b1.z) | ((u32)f2bf(b1.w) << 16);
        *(uint4*)&As[lrow][lc8] = ap;
        *(uint4*)&Bs[lrow][lc8] = bp;
        __syncthreads();
        #pragma unroll
        for (int ri = 0; ri < 2; ri++) {
            bf16x8 af = *(const bf16x8*)&As[wm * 32 + ri * 16 + r][kq];
            #pragma unroll
            for (int ci = 0; ci < 2; ci++) {
                bf16x8 bfr = *(const bf16x8*)&Bs[wn * 32 + ci * 16 + r][kq];
                acc[ri][ci] = __builtin_amdgcn_mfma_f32_16x16x32_bf16(af, bfr, acc[ri][ci], 0, 0, 0);
            }
        }
        __syncthreads();
    }

    #pragma unroll
    for (int ri = 0; ri < 2; ri++)
    #pragma unroll
    for (int ci = 0; ci < 2; ci++) {
        int col = bn + wn * 32 + ci * 16 + (lane & 15);
        int row0 = bm + wm * 32 + ri * 16 + (lane >> 4) * 4;
        #pragma unroll
        for (int reg = 0; reg < 4; reg++) {
            size_t idx = (size_t)(row0 + reg) * N + col;
            float v = acc[ri][ci][reg];
            if (ADD_SKIP) v += skip[idx];
            C[idx] = v;
        }
    }
}

// ---------------- K4: q/k head-normalize (*sqrt(scale)) + RoPE, in-place on fp32 qkv
__global__ __launch_bounds__(256) void qknorm_rope_kernel(
    float* __restrict__ qkv, const float* __restrict__ pos, const float* __restrict__ scale)
{
    int lane = threadIdx.x & 63;
    int wid = blockIdx.x * 4 + (threadIdx.x >> 6); // qk(1)|p(11)|h(3)
    int h = wid & 7;
    int p = (wid >> 3) & 2047;
    int qk = wid >> 14;
    size_t idx = (size_t)p * 1536 + qk * 512 + h * 64 + lane;
    float v = qkv[idx];
    float ss = v * v;
    #pragma unroll
    for (int d = 1; d < 64; d <<= 1) ss += __shfl_xor(ss, d);
    float sc = sqrtf(scale[h]) * rsqrtf(ss + 1e-6f);
    v *= sc;
    float partner = __shfl_xor(v, 16);
    float res = v;
    if (lane < 32) {
        int t = lane & 15;
        // freqs[h][t] = pi * 10^((t*8+h)/128)
        float fr = 3.14159265358979323846f * expf((float)(t * 8 + h) * (2.302585092994046f / 128.f));
        float th = pos[p] * fr;
        float cs = cosf(th), sn = sinf(th);
        res = (lane < 16) ? (v * cs - partner * sn) : (v * cs + partner * sn);
    }
    qkv[idx] = res;
}

// ---------------- K5: 7x7 neighborhood attention. One wave per (token, head).
// K tile in LDS as bf16 (stride 66 u16 = 33 u32): LDS 28KB/block -> 5 blocks/CU.
__global__ __launch_bounds__(256) void attn_kernel(
    const float* __restrict__ qkv, float* __restrict__ o)
{
    __shared__ u32 klu[4][49 * 33];   // bf16 pairs, row stride 33 dwords
    __shared__ float qls[4][64];
    __shared__ float pls[4][64];
    int w = threadIdx.x >> 6, lane = threadIdx.x & 63;
    int wid = blockIdx.x * 4 + w;  // 0..16383
    int h = wid & 7, p = wid >> 3;
    int n = p >> 10, i = (p >> 5) & 31, j = p & 31;
    int si = min(max(i - 3, 0), 25), sj = min(max(j - 3, 0), 25);

    qls[w][lane] = qkv[(size_t)p * 1536 + h * 64 + lane];
    u16* kls = (u16*)klu[w];
    {
        int ia = si, cj = 0;
        for (int a = 0; a < 49; a++) {
            int pp = n * 1024 + ia * 32 + (sj + cj);
            kls[a * 66 + lane] = f2bf(qkv[(size_t)pp * 1536 + 512 + h * 64 + lane]);
            if (++cj == 7) { cj = 0; ia++; }
        }
    }
    __syncthreads();

    float score = -1e30f;
    if (lane < 49) {
        float s = 0.f;
        const u32* kr = &klu[w][lane * 33];
        const float* qr = qls[w];
        #pragma unroll 8
        for (int e2 = 0; e2 < 32; e2++) {
            u32 v = kr[e2];
            s += qr[2 * e2] * bf2f((u16)(v & 0xffff))
               + qr[2 * e2 + 1] * bf2f((u16)(v >> 16));
        }
        score = s;
    }
    float m = score;
    #pragma unroll
    for (int d = 1; d < 64; d <<= 1) m = fmaxf(m, __shfl_xor(m, d));
    float ex = (lane < 49) ? expf(score - m) : 0.f;
    float s = ex;
    #pragma unroll
    for (int d = 1; d < 64; d <<= 1) s += __shfl_xor(s, d);
    pls[w][lane] = ex / s;
    __syncthreads();

    float acc = 0.f;
    {
        int ia = si, cj = 0;
        for (int a = 0; a < 49; a++) {
            int pp = n * 1024 + ia * 32 + (sj + cj);
            acc += pls[w][a] * qkv[(size_t)pp * 1536 + 1024 + h * 64 + lane];
            if (++cj == 7) { cj = 0; ia++; }
        }
    }
    o[(size_t)p * 512 + h * 64 + lane] = acc;
}

extern "C" void kernel_launch(void* const* d_in, const int* in_sizes, int n_in,
                              void* d_out, int out_size, void* d_ws, size_t ws_size,
                              hipStream_t stream)
{
    // Match inputs by unique element count (robust to ordering).
    const float *x = nullptr, *pos = nullptr, *cond = nullptr, *w_cond = nullptr,
                *w_qkv = nullptr, *scale = nullptr, *w_out = nullptr;
    for (int i = 0; i < n_in; i++) {
        switch (in_sizes[i]) {
            case 1048576: x      = (const float*)d_in[i]; break;  // 2*32*32*512
            case 2048:    pos    = (const float*)d_in[i]; break;  // 2*32*32*1
            case 1536:    cond   = (const float*)d_in[i]; break;  // 2*768
            case 393216:  w_cond = (const float*)d_in[i]; break;  // 512*768
            case 786432:  w_qkv  = (const float*)d_in[i]; break;  // 1536*512
            case 8:       scale  = (const float*)d_in[i]; break;  // 8
            case 262144:  w_out  = (const float*)d_in[i]; break;  // 512*512
            default: break;
        }
    }
    float* out = (float*)d_out;   // FLOAT32 output

    // ws: ns 4KB | inv 8KB | qkv 12MB | ob 4MB  (~16.6 MB)
    char* ws = (char*)d_ws;
    float* ns  = (float*)ws;                       // [2][512]
    float* inv = (float*)(ws + 4096);              // [2048]
    float* qkv = (float*)(ws + 12288);             // [2048][1536]
    float* ob  = (float*)(ws + 12288 + 12582912);  // [2048][512]

    setup_kernel<<<768, 256, 0, stream>>>(cond, w_cond, x, ns, inv);
    gemm_mfma<true, false><<<dim3(32, 24), 256, 0, stream>>>(x, ns, inv, w_qkv, qkv, nullptr, 1536, 512);
    qknorm_rope_kernel<<<8192, 256, 0, stream>>>(qkv, pos, scale);
    attn_kernel<<<4096, 256, 0, stream>>>(qkv, ob);
    gemm_mfma<false, true><<<dim3(32, 8), 256, 0, stream>>>(ob, nullptr, nullptr, w_out, out, x, 512, 512);
}

// Round 8
// 129.479 us; speedup vs baseline: 1.7917x; 1.3287x over previous
//
#include <hip/hip_runtime.h>

typedef unsigned short u16;
typedef unsigned int u32;
typedef __bf16 bf16x8 __attribute__((ext_vector_type(8)));
typedef float f32x4 __attribute__((ext_vector_type(4)));

__device__ __forceinline__ float bf2f(u16 v) {
    union { u32 u; float f; } c; c.u = ((u32)v) << 16; return c.f;
}
__device__ __forceinline__ u16 f2bf(float f) {
    union { float f; u32 u; } c; c.f = f;
    u32 u = c.u + 0x7fffu + ((c.u >> 16) & 1u);   // RNE
    return (u16)(u >> 16);
}

// ---------------- K1: fused cond_scale (blocks 0..255) + rms_inv (blocks 256..767)
__global__ __launch_bounds__(256) void setup_kernel(
    const float* __restrict__ cond, const float* __restrict__ w_cond,
    const float* __restrict__ x, float* __restrict__ ns, float* __restrict__ inv)
{
    int lane = threadIdx.x & 63;
    int b = blockIdx.x;
    if (b < 256) {
        int wid = b * 4 + (threadIdx.x >> 6); // 0..1023
        int n = wid >> 9, c = wid & 511;
        const float* cp = cond + n * 768;
        const float* wp = w_cond + (size_t)c * 768;
        float s = 0.f;
        #pragma unroll
        for (int j = 0; j < 12; j++)
            s += cp[lane + j * 64] * wp[lane + j * 64];
        #pragma unroll
        for (int d = 1; d < 64; d <<= 1) s += __shfl_xor(s, d);
        if (lane == 0) ns[wid] = s + 1.f;
    } else {
        int p = (b - 256) * 4 + (threadIdx.x >> 6); // 0..2047
        const float* xp = x + (size_t)p * 512;
        float s = 0.f;
        #pragma unroll
        for (int j = 0; j < 8; j++) { float v = xp[lane + j * 64]; s += v * v; }
        #pragma unroll
        for (int d = 1; d < 64; d <<= 1) s += __shfl_xor(s, d);
        if (lane == 0) inv[p] = rsqrtf(s * (1.f / 512.f) + 1e-6f);
    }
}

// ---------------- K2: bf16 conversions. blocks 0..1023: xn = rmsnorm(x)*ns (fused);
// blocks 1024..1791: w_qkv -> bf16 ; blocks 1792..2047: w_out -> bf16
__global__ __launch_bounds__(256) void convert_kernel(
    const float* __restrict__ x, const float* __restrict__ ns, const float* __restrict__ inv,
    const float* __restrict__ w_qkv, const float* __restrict__ w_out,
    u16* __restrict__ xn, u16* __restrict__ wqkvb, u16* __restrict__ woutb)
{
    int b = blockIdx.x;
    const float* src; u16* dst; size_t i4;
    bool rms = false;
    if (b < 1024)      { src = x;     dst = xn;    i4 = (size_t)(b)        * 1024 + threadIdx.x * 4; rms = true; }
    else if (b < 1792) { src = w_qkv; dst = wqkvb; i4 = (size_t)(b - 1024) * 1024 + threadIdx.x * 4; }
    else               { src = w_out; dst = woutb; i4 = (size_t)(b - 1792) * 1024 + threadIdx.x * 4; }
    float4 v = *(const float4*)(src + i4);
    if (rms) {
        int p = (int)(i4 >> 9), c = (int)(i4 & 511);
        float iv = inv[p];
        float4 nv = *(const float4*)(ns + (p >> 10) * 512 + c);
        v.x *= nv.x * iv; v.y *= nv.y * iv; v.z *= nv.z * iv; v.w *= nv.w * iv;
    }
    ushort4 o; o.x = f2bf(v.x); o.y = f2bf(v.y); o.z = f2bf(v.z); o.w = f2bf(v.w);
    *(ushort4*)(dst + i4) = o;
}

// ---------------- MFMA GEMM: C[M][N](fp32) = A[M][K] @ B[N][K]^T, bf16 in, fp32 acc.
// Block tile 64x64, 4 waves 2x2, mfma_f32_16x16x32_bf16.
// A-frag: m=lane&15, k=(lane>>4)*8+j ; C/D: col(N)=lane&15, row(M)=(lane>>4)*4+reg [m89/m91]
template<bool ADD_SKIP>
__global__ __launch_bounds__(256) void gemm_bt(
    const u16* __restrict__ A, const u16* __restrict__ B,
    float* __restrict__ C, const float* __restrict__ skip,
    int N, int K)
{
    __shared__ __align__(16) u16 As[64][40];
    __shared__ __align__(16) u16 Bs[64][40];
    int tid = threadIdx.x;
    int lane = tid & 63;
    int w = tid >> 6;
    int wm = w >> 1, wn = w & 1;
    int bm = blockIdx.x * 64, bn = blockIdx.y * 64;
    int lrow = tid >> 2, lc8 = (tid & 3) * 8;

    f32x4 zero = {0.f, 0.f, 0.f, 0.f};
    f32x4 acc[2][2];
    acc[0][0] = zero; acc[0][1] = zero; acc[1][0] = zero; acc[1][1] = zero;

    const u16* Ap = A + (size_t)(bm + lrow) * K + lc8;
    const u16* Bp = B + (size_t)(bn + lrow) * K + lc8;
    int r = lane & 15, kq = (lane >> 4) * 8;

    for (int k0 = 0; k0 < K; k0 += 32) {
        *(uint4*)&As[lrow][lc8] = *(const uint4*)(Ap + k0);
        *(uint4*)&Bs[lrow][lc8] = *(const uint4*)(Bp + k0);
        __syncthreads();
        #pragma unroll
        for (int ri = 0; ri < 2; ri++) {
            bf16x8 af = *(const bf16x8*)&As[wm * 32 + ri * 16 + r][kq];
            #pragma unroll
            for (int ci = 0; ci < 2; ci++) {
                bf16x8 bfr = *(const bf16x8*)&Bs[wn * 32 + ci * 16 + r][kq];
                acc[ri][ci] = __builtin_amdgcn_mfma_f32_16x16x32_bf16(af, bfr, acc[ri][ci], 0, 0, 0);
            }
        }
        __syncthreads();
    }

    #pragma unroll
    for (int ri = 0; ri < 2; ri++)
    #pragma unroll
    for (int ci = 0; ci < 2; ci++) {
        int col = bn + wn * 32 + ci * 16 + (lane & 15);
        int row0 = bm + wm * 32 + ri * 16 + (lane >> 4) * 4;
        #pragma unroll
        for (int reg = 0; reg < 4; reg++) {
            size_t idx = (size_t)(row0 + reg) * N + col;
            float v = acc[ri][ci][reg];
            if (ADD_SKIP) v += skip[idx];
            C[idx] = v;
        }
    }
}

// ---------------- K4: q/k head-normalize (*sqrt(scale)) + RoPE, in-place on fp32 qkv
__global__ __launch_bounds__(256) void qknorm_rope_kernel(
    float* __restrict__ qkv, const float* __restrict__ pos, const float* __restrict__ scale)
{
    int lane = threadIdx.x & 63;
    int wid = blockIdx.x * 4 + (threadIdx.x >> 6); // qk(1)|p(11)|h(3)
    int h = wid & 7;
    int p = (wid >> 3) & 2047;
    int qk = wid >> 14;
    size_t idx = (size_t)p * 1536 + qk * 512 + h * 64 + lane;
    float v = qkv[idx];
    float ss = v * v;
    #pragma unroll
    for (int d = 1; d < 64; d <<= 1) ss += __shfl_xor(ss, d);
    float sc = sqrtf(scale[h]) * rsqrtf(ss + 1e-6f);
    v *= sc;
    float partner = __shfl_xor(v, 16);
    float res = v;
    if (lane < 32) {
        int t = lane & 15;
        // freqs[h][t] = pi * 10^((t*8+h)/128)
        float fr = 3.14159265358979323846f * expf((float)(t * 8 + h) * (2.302585092994046f / 128.f));
        float th = pos[p] * fr;
        float cs = cosf(th), sn = sinf(th);
        res = (lane < 16) ? (v * cs - partner * sn) : (v * cs + partner * sn);
    }
    qkv[idx] = res;
}

// ---------------- K5: 7x7 neighborhood attention. One wave per (token, head).
// Fully-unrolled staging & PV (compile-time neighbor offsets -> deep load pipelining).
// Softmax probs broadcast via __shfl (no pls LDS). K tile bf16 stride-66. ob is bf16.
__global__ __launch_bounds__(256) void attn_kernel(
    const float* __restrict__ qkv, u16* __restrict__ o)
{
    __shared__ u32 klu[4][49 * 33];   // bf16 pairs, row stride 33 dwords
    __shared__ float qls[4][64];
    int w = threadIdx.x >> 6, lane = threadIdx.x & 63;
    int wid = blockIdx.x * 4 + w;  // 0..16383
    int h = wid & 7, p = wid >> 3;
    int n = p >> 10, i = (p >> 5) & 31, j = p & 31;
    int si = min(max(i - 3, 0), 25), sj = min(max(j - 3, 0), 25);

    qls[w][lane] = qkv[(size_t)p * 1536 + h * 64 + lane];
    u16* kls = (u16*)klu[w];
    {
        const float* kb = qkv + (size_t)(n * 1024 + si * 32 + sj) * 1536 + 512 + h * 64 + lane;
        #pragma unroll
        for (int a = 0; a < 49; a++)
            kls[a * 66 + lane] = f2bf(kb[(size_t)((a / 7) * 32 + (a % 7)) * 1536]);
    }
    __syncthreads();

    float score = -1e30f;
    if (lane < 49) {
        float s = 0.f;
        const u32* kr = &klu[w][lane * 33];
        const float* qr = qls[w];
        #pragma unroll
        for (int e2 = 0; e2 < 32; e2++) {
            u32 v = kr[e2];
            s += qr[2 * e2] * bf2f((u16)(v & 0xffff))
               + qr[2 * e2 + 1] * bf2f((u16)(v >> 16));
        }
        score = s;
    }
    float m = score;
    #pragma unroll
    for (int d = 1; d < 64; d <<= 1) m = fmaxf(m, __shfl_xor(m, d));
    float ex = (lane < 49) ? expf(score - m) : 0.f;
    float s = ex;
    #pragma unroll
    for (int d = 1; d < 64; d <<= 1) s += __shfl_xor(s, d);
    float pr = ex * __frcp_rn(s);   // lane a holds prob of neighbor a

    float acc = 0.f;
    {
        const float* vb = qkv + (size_t)(n * 1024 + si * 32 + sj) * 1536 + 1024 + h * 64 + lane;
        #pragma unroll
        for (int a = 0; a < 49; a++)
            acc += __shfl(pr, a) * vb[(size_t)((a / 7) * 32 + (a % 7)) * 1536];
    }
    o[(size_t)p * 512 + h * 64 + lane] = f2bf(acc);
}

extern "C" void kernel_launch(void* const* d_in, const int* in_sizes, int n_in,
                              void* d_out, int out_size, void* d_ws, size_t ws_size,
                              hipStream_t stream)
{
    // Match inputs by unique element count (robust to ordering).
    const float *x = nullptr, *pos = nullptr, *cond = nullptr, *w_cond = nullptr,
                *w_qkv = nullptr, *scale = nullptr, *w_out = nullptr;
    for (int i = 0; i < n_in; i++) {
        switch (in_sizes[i]) {
            case 1048576: x      = (const float*)d_in[i]; break;  // 2*32*32*512
            case 2048:    pos    = (const float*)d_in[i]; break;  // 2*32*32*1
            case 1536:    cond   = (const float*)d_in[i]; break;  // 2*768
            case 393216:  w_cond = (const float*)d_in[i]; break;  // 512*768
            case 786432:  w_qkv  = (const float*)d_in[i]; break;  // 1536*512
            case 8:       scale  = (const float*)d_in[i]; break;  // 8
            case 262144:  w_out  = (const float*)d_in[i]; break;  // 512*512
            default: break;
        }
    }
    float* out = (float*)d_out;   // FLOAT32 output

    // ws: ns 4KB | inv 8KB | qkv fp32 12MB | xn 2MB | wqkvb 1.5MB | woutb 0.5MB | ob 2MB
    char* ws = (char*)d_ws;
    float* ns    = (float*)ws;                          // [2][512]
    float* inv   = (float*)(ws + 4096);                 // [2048]
    float* qkv   = (float*)(ws + 12288);                // [2048][1536] fp32
    u16*   xn    = (u16*)(ws + 12288 + 12582912);       // [2048][512]  bf16
    u16*   wqkvb = (u16*)(ws + 12288 + 14680064);       // [1536][512]  bf16
    u16*   woutb = (u16*)(ws + 12288 + 16252928);       // [512][512]   bf16
    u16*   ob    = (u16*)(ws + 12288 + 16777216);       // [2048][512]  bf16

    setup_kernel<<<768, 256, 0, stream>>>(cond, w_cond, x, ns, inv);
    convert_kernel<<<2048, 256, 0, stream>>>(x, ns, inv, w_qkv, w_out, xn, wqkvb, woutb);
    gemm_bt<false><<<dim3(32, 24), 256, 0, stream>>>(xn, wqkvb, qkv, nullptr, 1536, 512);
    qknorm_rope_kernel<<<8192, 256, 0, stream>>>(qkv, pos, scale);
    attn_kernel<<<4096, 256, 0, stream>>>(qkv, ob);
    gemm_bt<true><<<dim3(32, 8), 256, 0, stream>>>(ob, woutb, out, x, 512, 512);
}

// Round 9
// 128.219 us; speedup vs baseline: 1.8093x; 1.0098x over previous
//
#include <hip/hip_runtime.h>

typedef unsigned short u16;
typedef unsigned int u32;
typedef __bf16 bf16x8 __attribute__((ext_vector_type(8)));
typedef float f32x4 __attribute__((ext_vector_type(4)));

__device__ __forceinline__ float bf2f(u16 v) {
    union { u32 u; float f; } c; c.u = ((u32)v) << 16; return c.f;
}
__device__ __forceinline__ u16 f2bf(float f) {
    union { float f; u32 u; } c; c.f = f;
    u32 u = c.u + 0x7fffu + ((c.u >> 16) & 1u);   // RNE
    return (u16)(u >> 16);
}

// ---------------- K1: fused cond_scale (blocks 0..255) + rms_inv (blocks 256..767)
__global__ __launch_bounds__(256) void setup_kernel(
    const float* __restrict__ cond, const float* __restrict__ w_cond,
    const float* __restrict__ x, float* __restrict__ ns, float* __restrict__ inv)
{
    int lane = threadIdx.x & 63;
    int b = blockIdx.x;
    if (b < 256) {
        int wid = b * 4 + (threadIdx.x >> 6); // 0..1023
        int n = wid >> 9, c = wid & 511;
        const float* cp = cond + n * 768;
        const float* wp = w_cond + (size_t)c * 768;
        float s = 0.f;
        #pragma unroll
        for (int j = 0; j < 12; j++)
            s += cp[lane + j * 64] * wp[lane + j * 64];
        #pragma unroll
        for (int d = 1; d < 64; d <<= 1) s += __shfl_xor(s, d);
        if (lane == 0) ns[wid] = s + 1.f;
    } else {
        int p = (b - 256) * 4 + (threadIdx.x >> 6); // 0..2047
        const float* xp = x + (size_t)p * 512;
        float s = 0.f;
        #pragma unroll
        for (int j = 0; j < 8; j++) { float v = xp[lane + j * 64]; s += v * v; }
        #pragma unroll
        for (int d = 1; d < 64; d <<= 1) s += __shfl_xor(s, d);
        if (lane == 0) inv[p] = rsqrtf(s * (1.f / 512.f) + 1e-6f);
    }
}

// ---------------- K2: bf16 conversions. blocks 0..1023: xn = rmsnorm(x)*ns (fused);
// blocks 1024..1791: w_qkv -> bf16 ; blocks 1792..2047: w_out -> bf16
__global__ __launch_bounds__(256) void convert_kernel(
    const float* __restrict__ x, const float* __restrict__ ns, const float* __restrict__ inv,
    const float* __restrict__ w_qkv, const float* __restrict__ w_out,
    u16* __restrict__ xn, u16* __restrict__ wqkvb, u16* __restrict__ woutb)
{
    int b = blockIdx.x;
    const float* src; u16* dst; size_t i4;
    bool rms = false;
    if (b < 1024)      { src = x;     dst = xn;    i4 = (size_t)(b)        * 1024 + threadIdx.x * 4; rms = true; }
    else if (b < 1792) { src = w_qkv; dst = wqkvb; i4 = (size_t)(b - 1024) * 1024 + threadIdx.x * 4; }
    else               { src = w_out; dst = woutb; i4 = (size_t)(b - 1792) * 1024 + threadIdx.x * 4; }
    float4 v = *(const float4*)(src + i4);
    if (rms) {
        int p = (int)(i4 >> 9), c = (int)(i4 & 511);
        float iv = inv[p];
        float4 nv = *(const float4*)(ns + (p >> 10) * 512 + c);
        v.x *= nv.x * iv; v.y *= nv.y * iv; v.z *= nv.z * iv; v.w *= nv.w * iv;
    }
    ushort4 o; o.x = f2bf(v.x); o.y = f2bf(v.y); o.z = f2bf(v.z); o.w = f2bf(v.w);
    *(ushort4*)(dst + i4) = o;
}

// ---------------- MFMA GEMM: C[M][N] = A[M][K] @ B[N][K]^T, bf16 in, fp32 acc.
// Block tile 64x64, 4 waves 2x2, mfma_f32_16x16x32_bf16.
// A-frag: m=lane&15, k=(lane>>4)*8+j ; C/D: col(N)=lane&15, row(M)=(lane>>4)*4+reg [m89/m91]
template<bool OUT_BF16, bool ADD_SKIP>
__global__ __launch_bounds__(256) void gemm_bt(
    const u16* __restrict__ A, const u16* __restrict__ B,
    float* __restrict__ Cf, u16* __restrict__ Cb, const float* __restrict__ skip,
    int N, int K)
{
    __shared__ __align__(16) u16 As[64][40];
    __shared__ __align__(16) u16 Bs[64][40];
    int tid = threadIdx.x;
    int lane = tid & 63;
    int w = tid >> 6;
    int wm = w >> 1, wn = w & 1;
    int bm = blockIdx.x * 64, bn = blockIdx.y * 64;
    int lrow = tid >> 2, lc8 = (tid & 3) * 8;

    f32x4 zero = {0.f, 0.f, 0.f, 0.f};
    f32x4 acc[2][2];
    acc[0][0] = zero; acc[0][1] = zero; acc[1][0] = zero; acc[1][1] = zero;

    const u16* Ap = A + (size_t)(bm + lrow) * K + lc8;
    const u16* Bp = B + (size_t)(bn + lrow) * K + lc8;
    int r = lane & 15, kq = (lane >> 4) * 8;

    for (int k0 = 0; k0 < K; k0 += 32) {
        *(uint4*)&As[lrow][lc8] = *(const uint4*)(Ap + k0);
        *(uint4*)&Bs[lrow][lc8] = *(const uint4*)(Bp + k0);
        __syncthreads();
        #pragma unroll
        for (int ri = 0; ri < 2; ri++) {
            bf16x8 af = *(const bf16x8*)&As[wm * 32 + ri * 16 + r][kq];
            #pragma unroll
            for (int ci = 0; ci < 2; ci++) {
                bf16x8 bfr = *(const bf16x8*)&Bs[wn * 32 + ci * 16 + r][kq];
                acc[ri][ci] = __builtin_amdgcn_mfma_f32_16x16x32_bf16(af, bfr, acc[ri][ci], 0, 0, 0);
            }
        }
        __syncthreads();
    }

    #pragma unroll
    for (int ri = 0; ri < 2; ri++)
    #pragma unroll
    for (int ci = 0; ci < 2; ci++) {
        int col = bn + wn * 32 + ci * 16 + (lane & 15);
        int row0 = bm + wm * 32 + ri * 16 + (lane >> 4) * 4;
        #pragma unroll
        for (int reg = 0; reg < 4; reg++) {
            size_t idx = (size_t)(row0 + reg) * N + col;
            float v = acc[ri][ci][reg];
            if (ADD_SKIP) v += skip[idx];
            if (OUT_BF16) Cb[idx] = f2bf(v);
            else Cf[idx] = v;
        }
    }
}

// ---------------- K4: q/k normalize (*sqrt(scale)) + RoPE; v passthrough.
// Reads bf16 qkvb[2048][1536]; writes head-major bf16 planes [n][h][1024][64].
__global__ __launch_bounds__(256) void rope_plane_kernel(
    const u16* __restrict__ qkvb, const float* __restrict__ pos, const float* __restrict__ scale,
    u16* __restrict__ qp, u16* __restrict__ kp, u16* __restrict__ vp)
{
    int lane = threadIdx.x & 63;
    int wid = blockIdx.x * 4 + (threadIdx.x >> 6); // 0..49151
    int qk = wid >> 14;            // 0=q 1=k 2=v
    int rem = wid & 16383;
    int h = rem & 7, p = rem >> 3; // p 0..2047
    float v = bf2f(qkvb[(size_t)p * 1536 + qk * 512 + h * 64 + lane]);
    float res = v;
    if (qk < 2) {
        float ss = v * v;
        #pragma unroll
        for (int d = 1; d < 64; d <<= 1) ss += __shfl_xor(ss, d);
        float sc = sqrtf(scale[h]) * rsqrtf(ss + 1e-6f);
        v *= sc;
        float partner = __shfl_xor(v, 16);
        res = v;
        if (lane < 32) {
            int t = lane & 15;
            // freqs[h][t] = pi * 10^((t*8+h)/128)
            float fr = 3.14159265358979323846f * expf((float)(t * 8 + h) * (2.302585092994046f / 128.f));
            float th = pos[p] * fr;
            float cs = cosf(th), sn = sinf(th);
            res = (lane < 16) ? (v * cs - partner * sn) : (v * cs + partner * sn);
        }
    }
    u16* plane = (qk == 0) ? qp : (qk == 1) ? kp : vp;
    // dst token index within plane: n=p>>10, pi=p&1023 -> ((n*8+h)*1024+pi)*64+lane
    size_t dst = ((size_t)((p >> 10) * 8 + h) * 1024 + (p & 1023)) * 64 + lane;
    plane[dst] = f2bf(res);
}

// ---------------- K5: 7x7 neighborhood attention. One wave per (token, head).
// bf16 head-major planes; LDS K-tile staging is raw u16 copy; PV reads bf16.
__global__ __launch_bounds__(256) void attn_kernel(
    const u16* __restrict__ qp, const u16* __restrict__ kp, const u16* __restrict__ vp,
    u16* __restrict__ o)
{
    __shared__ u32 klu[4][49 * 33];   // bf16 pairs, row stride 33 dwords
    __shared__ float qls[4][64];
    int w = threadIdx.x >> 6, lane = threadIdx.x & 63;
    int wid = blockIdx.x * 4 + w;  // 0..16383
    int h = wid & 7, p = wid >> 3;
    int n = p >> 10, i = (p >> 5) & 31, j = p & 31;
    int si = min(max(i - 3, 0), 25), sj = min(max(j - 3, 0), 25);

    size_t base = (size_t)(n * 8 + h) * 1024 * 64;
    qls[w][lane] = bf2f(qp[base + (size_t)(p & 1023) * 64 + lane]);
    u16* kls = (u16*)klu[w];
    {
        const u16* kb = kp + base + (size_t)(si * 32 + sj) * 64 + lane;
        #pragma unroll
        for (int a = 0; a < 49; a++)
            kls[a * 66 + lane] = kb[((a / 7) * 32 + (a % 7)) * 64];
    }
    __syncthreads();

    float score = -1e30f;
    if (lane < 49) {
        float s = 0.f;
        const u32* kr = &klu[w][lane * 33];
        const float* qr = qls[w];
        #pragma unroll
        for (int e2 = 0; e2 < 32; e2++) {
            u32 v = kr[e2];
            s += qr[2 * e2] * bf2f((u16)(v & 0xffff))
               + qr[2 * e2 + 1] * bf2f((u16)(v >> 16));
        }
        score = s;
    }
    float m = score;
    #pragma unroll
    for (int d = 1; d < 64; d <<= 1) m = fmaxf(m, __shfl_xor(m, d));
    float ex = (lane < 49) ? expf(score - m) : 0.f;
    float s = ex;
    #pragma unroll
    for (int d = 1; d < 64; d <<= 1) s += __shfl_xor(s, d);
    float pr = ex * __frcp_rn(s);   // lane a holds prob of neighbor a

    float acc = 0.f;
    {
        const u16* vb = vp + base + (size_t)(si * 32 + sj) * 64 + lane;
        #pragma unroll
        for (int a = 0; a < 49; a++)
            acc += __shfl(pr, a) * bf2f(vb[((a / 7) * 32 + (a % 7)) * 64]);
    }
    o[(size_t)p * 512 + h * 64 + lane] = f2bf(acc);
}

extern "C" void kernel_launch(void* const* d_in, const int* in_sizes, int n_in,
                              void* d_out, int out_size, void* d_ws, size_t ws_size,
                              hipStream_t stream)
{
    // Match inputs by unique element count (robust to ordering).
    const float *x = nullptr, *pos = nullptr, *cond = nullptr, *w_cond = nullptr,
                *w_qkv = nullptr, *scale = nullptr, *w_out = nullptr;
    for (int i = 0; i < n_in; i++) {
        switch (in_sizes[i]) {
            case 1048576: x      = (const float*)d_in[i]; break;  // 2*32*32*512
            case 2048:    pos    = (const float*)d_in[i]; break;  // 2*32*32*1
            case 1536:    cond   = (const float*)d_in[i]; break;  // 2*768
            case 393216:  w_cond = (const float*)d_in[i]; break;  // 512*768
            case 786432:  w_qkv  = (const float*)d_in[i]; break;  // 1536*512
            case 8:       scale  = (const float*)d_in[i]; break;  // 8
            case 262144:  w_out  = (const float*)d_in[i]; break;  // 512*512
            default: break;
        }
    }
    float* out = (float*)d_out;   // FLOAT32 output

    // ws: ns 4K | inv 8K | qkvb 6M | xn 2M | wqkvb 1.5M | woutb .5M | qp/kp/vp 6M | ob 2M
    char* ws = (char*)d_ws;
    float* ns    = (float*)ws;                          // [2][512]
    float* inv   = (float*)(ws + 4096);                 // [2048]
    u16*   qkvb  = (u16*)(ws + 12288);                  // [2048][1536] bf16
    u16*   xn    = (u16*)(ws + 12288 + 6291456);        // [2048][512]  bf16
    u16*   wqkvb = (u16*)(ws + 12288 + 8388608);        // [1536][512]  bf16
    u16*   woutb = (u16*)(ws + 12288 + 9961472);        // [512][512]   bf16
    u16*   qp    = (u16*)(ws + 12288 + 10485760);       // [2][8][1024][64] bf16
    u16*   kp    = (u16*)(ws + 12288 + 12582912);       // same
    u16*   vp    = (u16*)(ws + 12288 + 14680064);       // same
    u16*   ob    = (u16*)(ws + 12288 + 16777216);       // [2048][512]  bf16

    setup_kernel<<<768, 256, 0, stream>>>(cond, w_cond, x, ns, inv);
    convert_kernel<<<2048, 256, 0, stream>>>(x, ns, inv, w_qkv, w_out, xn, wqkvb, woutb);
    gemm_bt<true, false><<<dim3(32, 24), 256, 0, stream>>>(xn, wqkvb, nullptr, qkvb, nullptr, 1536, 512);
    rope_plane_kernel<<<12288, 256, 0, stream>>>(qkvb, pos, scale, qp, kp, vp);
    attn_kernel<<<4096, 256, 0, stream>>>(qp, kp, vp, ob);
    gemm_bt<false, true><<<dim3(32, 8), 256, 0, stream>>>(ob, woutb, out, nullptr, x, 512, 512);
}

// Round 10
// 121.110 us; speedup vs baseline: 1.9155x; 1.0587x over previous
//
#include <hip/hip_runtime.h>

typedef unsigned short u16;
typedef unsigned int u32;
typedef __bf16 bf16x8 __attribute__((ext_vector_type(8)));
typedef float f32x4 __attribute__((ext_vector_type(4)));

__device__ __forceinline__ float bf2f(u16 v) {
    union { u32 u; float f; } c; c.u = ((u32)v) << 16; return c.f;
}
__device__ __forceinline__ u16 f2bf(float f) {
    union { float f; u32 u; } c; c.f = f;
    u32 u = c.u + 0x7fffu + ((c.u >> 16) & 1u);   // RNE
    return (u16)(u >> 16);
}

// ---------------- K1: fused cond_scale (blocks 0..255) + rms_inv (blocks 256..767)
__global__ __launch_bounds__(256) void setup_kernel(
    const float* __restrict__ cond, const float* __restrict__ w_cond,
    const float* __restrict__ x, float* __restrict__ ns, float* __restrict__ inv)
{
    int lane = threadIdx.x & 63;
    int b = blockIdx.x;
    if (b < 256) {
        int wid = b * 4 + (threadIdx.x >> 6); // 0..1023
        int n = wid >> 9, c = wid & 511;
        const float* cp = cond + n * 768;
        const float* wp = w_cond + (size_t)c * 768;
        float s = 0.f;
        #pragma unroll
        for (int j = 0; j < 12; j++)
            s += cp[lane + j * 64] * wp[lane + j * 64];
        #pragma unroll
        for (int d = 1; d < 64; d <<= 1) s += __shfl_xor(s, d);
        if (lane == 0) ns[wid] = s + 1.f;
    } else {
        int p = (b - 256) * 4 + (threadIdx.x >> 6); // 0..2047
        const float* xp = x + (size_t)p * 512;
        float s = 0.f;
        #pragma unroll
        for (int j = 0; j < 8; j++) { float v = xp[lane + j * 64]; s += v * v; }
        #pragma unroll
        for (int d = 1; d < 64; d <<= 1) s += __shfl_xor(s, d);
        if (lane == 0) inv[p] = rsqrtf(s * (1.f / 512.f) + 1e-6f);
    }
}

// ---------------- K2: bf16 conversions. blocks 0..1023: xn = rmsnorm(x)*ns (fused);
// blocks 1024..1791: w_qkv -> bf16 ; blocks 1792..2047: w_out -> bf16
__global__ __launch_bounds__(256) void convert_kernel(
    const float* __restrict__ x, const float* __restrict__ ns, const float* __restrict__ inv,
    const float* __restrict__ w_qkv, const float* __restrict__ w_out,
    u16* __restrict__ xn, u16* __restrict__ wqkvb, u16* __restrict__ woutb)
{
    int b = blockIdx.x;
    const float* src; u16* dst; size_t i4;
    bool rms = false;
    if (b < 1024)      { src = x;     dst = xn;    i4 = (size_t)(b)        * 1024 + threadIdx.x * 4; rms = true; }
    else if (b < 1792) { src = w_qkv; dst = wqkvb; i4 = (size_t)(b - 1024) * 1024 + threadIdx.x * 4; }
    else               { src = w_out; dst = woutb; i4 = (size_t)(b - 1792) * 1024 + threadIdx.x * 4; }
    float4 v = *(const float4*)(src + i4);
    if (rms) {
        int p = (int)(i4 >> 9), c = (int)(i4 & 511);
        float iv = inv[p];
        float4 nv = *(const float4*)(ns + (p >> 10) * 512 + c);
        v.x *= nv.x * iv; v.y *= nv.y * iv; v.z *= nv.z * iv; v.w *= nv.w * iv;
    }
    ushort4 o; o.x = f2bf(v.x); o.y = f2bf(v.y); o.z = f2bf(v.z); o.w = f2bf(v.w);
    *(ushort4*)(dst + i4) = o;
}

// ---------------- MFMA GEMM: C[M][N] = A[M][K] @ B[N][K]^T, bf16 in, fp32 acc.
// Block tile 64x64, 4 waves 2x2, mfma_f32_16x16x32_bf16.
// A-frag: m=lane&15, k=(lane>>4)*8+j ; C/D: col(N)=lane&15, row(M)=(lane>>4)*4+reg [m89/m91]
template<bool OUT_BF16, bool ADD_SKIP>
__global__ __launch_bounds__(256) void gemm_bt(
    const u16* __restrict__ A, const u16* __restrict__ B,
    float* __restrict__ Cf, u16* __restrict__ Cb, const float* __restrict__ skip,
    int N, int K)
{
    __shared__ __align__(16) u16 As[64][40];
    __shared__ __align__(16) u16 Bs[64][40];
    int tid = threadIdx.x;
    int lane = tid & 63;
    int w = tid >> 6;
    int wm = w >> 1, wn = w & 1;
    int bm = blockIdx.x * 64, bn = blockIdx.y * 64;
    int lrow = tid >> 2, lc8 = (tid & 3) * 8;

    f32x4 zero = {0.f, 0.f, 0.f, 0.f};
    f32x4 acc[2][2];
    acc[0][0] = zero; acc[0][1] = zero; acc[1][0] = zero; acc[1][1] = zero;

    const u16* Ap = A + (size_t)(bm + lrow) * K + lc8;
    const u16* Bp = B + (size_t)(bn + lrow) * K + lc8;
    int r = lane & 15, kq = (lane >> 4) * 8;

    for (int k0 = 0; k0 < K; k0 += 32) {
        *(uint4*)&As[lrow][lc8] = *(const uint4*)(Ap + k0);
        *(uint4*)&Bs[lrow][lc8] = *(const uint4*)(Bp + k0);
        __syncthreads();
        #pragma unroll
        for (int ri = 0; ri < 2; ri++) {
            bf16x8 af = *(const bf16x8*)&As[wm * 32 + ri * 16 + r][kq];
            #pragma unroll
            for (int ci = 0; ci < 2; ci++) {
                bf16x8 bfr = *(const bf16x8*)&Bs[wn * 32 + ci * 16 + r][kq];
                acc[ri][ci] = __builtin_amdgcn_mfma_f32_16x16x32_bf16(af, bfr, acc[ri][ci], 0, 0, 0);
            }
        }
        __syncthreads();
    }

    #pragma unroll
    for (int ri = 0; ri < 2; ri++)
    #pragma unroll
    for (int ci = 0; ci < 2; ci++) {
        int col = bn + wn * 32 + ci * 16 + (lane & 15);
        int row0 = bm + wm * 32 + ri * 16 + (lane >> 4) * 4;
        #pragma unroll
        for (int reg = 0; reg < 4; reg++) {
            size_t idx = (size_t)(row0 + reg) * N + col;
            float v = acc[ri][ci][reg];
            if (ADD_SKIP) v += skip[idx];
            if (OUT_BF16) Cb[idx] = f2bf(v);
            else Cf[idx] = v;
        }
    }
}

// ---------------- K4: q/k normalize (*sqrt(scale)) + RoPE; v passthrough.
// Reads bf16 qkvb[2048][1536]; writes head-major bf16 planes [n][h][1024][64].
__global__ __launch_bounds__(256) void rope_plane_kernel(
    const u16* __restrict__ qkvb, const float* __restrict__ pos, const float* __restrict__ scale,
    u16* __restrict__ qp, u16* __restrict__ kp, u16* __restrict__ vp)
{
    int lane = threadIdx.x & 63;
    int wid = blockIdx.x * 4 + (threadIdx.x >> 6); // 0..49151
    int qk = wid >> 14;            // 0=q 1=k 2=v
    int rem = wid & 16383;
    int h = rem & 7, p = rem >> 3; // p 0..2047
    float v = bf2f(qkvb[(size_t)p * 1536 + qk * 512 + h * 64 + lane]);
    float res = v;
    if (qk < 2) {
        float ss = v * v;
        #pragma unroll
        for (int d = 1; d < 64; d <<= 1) ss += __shfl_xor(ss, d);
        float sc = sqrtf(scale[h]) * rsqrtf(ss + 1e-6f);
        v *= sc;
        float partner = __shfl_xor(v, 16);
        res = v;
        if (lane < 32) {
            int t = lane & 15;
            // freqs[h][t] = pi * 10^((t*8+h)/128)
            float fr = 3.14159265358979323846f * expf((float)(t * 8 + h) * (2.302585092994046f / 128.f));
            float th = pos[p] * fr;
            float cs = cosf(th), sn = sinf(th);
            res = (lane < 16) ? (v * cs - partner * sn) : (v * cs + partner * sn);
        }
    }
    u16* plane = (qk == 0) ? qp : (qk == 1) ? kp : vp;
    size_t dst = ((size_t)((p >> 10) * 8 + h) * 1024 + (p & 1023)) * 64 + lane;
    plane[dst] = f2bf(res);
}

// ---------------- K5: MFMA neighborhood attention.
// One block per (n, h, 8x8 query tile). Union of neighborhoods = 14x14 = 196 keys.
// S = Q K^T via mfma (fp16 in LDS) -> masked softmax -> P (bf16, in place) -> P V via mfma.
__global__ __launch_bounds__(256) void attn_mfma(
    const u16* __restrict__ qp, const u16* __restrict__ kp, const u16* __restrict__ vp,
    u16* __restrict__ ob)
{
    __shared__ __align__(16) u16 Kb[208 * 72];   // K:[nb][64] stride 72; reused as Vt:[64][224] stride 234
    __shared__ __align__(16) u16 Sb[64 * 232];   // S fp16 then P bf16, row stride 232

    int tid = threadIdx.x, lane = tid & 63, w = tid >> 6;
    int bx = blockIdx.x;
    int n = bx >> 7, h = (bx >> 4) & 7, t = bx & 15;
    int ti = (t >> 2) * 8, tj = (t & 3) * 8;
    int r0 = min(max(ti - 3, 0), 18), c0 = min(max(tj - 3, 0), 18);
    const u16* qpl = qp + ((size_t)(n * 8 + h) << 16);
    const u16* kpl = kp + ((size_t)(n * 8 + h) << 16);
    const u16* vpl = vp + ((size_t)(n * 8 + h) << 16);

    // ---- stage K patch: 196 neighbors x 64 dims
    for (int g = tid; g < 1568; g += 256) {
        int nb = g >> 3, k8 = (g & 7) << 3;
        int ar = nb / 14, ac = nb - ar * 14;
        *(uint4*)&Kb[nb * 72 + k8] =
            *(const uint4*)&kpl[(size_t)((r0 + ar) * 32 + c0 + ac) * 64 + k8];
    }
    __syncthreads();

    // ---- S = Q K^T  (wave w = query m-tile)
    int m = lane & 15, quad = lane >> 4;
    {
        int r = w * 16 + m;                   // A-frag query row
        int tok = (ti + (r >> 3)) * 32 + (tj + (r & 7));
        bf16x8 qf0 = *(const bf16x8*)&qpl[(size_t)tok * 64 + quad * 8];
        bf16x8 qf1 = *(const bf16x8*)&qpl[(size_t)tok * 64 + 32 + quad * 8];
        _Float16* sp = (_Float16*)Sb;
        #pragma unroll
        for (int nt = 0; nt < 13; nt++) {
            f32x4 acc = {0.f, 0.f, 0.f, 0.f};
            bf16x8 b0 = *(const bf16x8*)&Kb[(nt * 16 + m) * 72 + quad * 8];
            bf16x8 b1 = *(const bf16x8*)&Kb[(nt * 16 + m) * 72 + 32 + quad * 8];
            acc = __builtin_amdgcn_mfma_f32_16x16x32_bf16(qf0, b0, acc, 0, 0, 0);
            acc = __builtin_amdgcn_mfma_f32_16x16x32_bf16(qf1, b1, acc, 0, 0, 0);
            #pragma unroll
            for (int reg = 0; reg < 4; reg++)
                sp[(w * 16 + quad * 4 + reg) * 232 + nt * 16 + m] = (_Float16)acc[reg];
        }
    }
    __syncthreads();

    // ---- stage V^T (reuse Kb): Vt[d][nb], stride 234; pad nb 196..223 = 0
    for (int g = tid; g < 1568; g += 256) {
        int nb = g >> 3, k8 = (g & 7) << 3;
        int ar = nb / 14, ac = nb - ar * 14;
        uint4 v4 = *(const uint4*)&vpl[(size_t)((r0 + ar) * 32 + c0 + ac) * 64 + k8];
        u32 uu[4] = {v4.x, v4.y, v4.z, v4.w};
        #pragma unroll
        for (int e = 0; e < 4; e++) {
            Kb[(k8 + 2 * e) * 234 + nb]     = (u16)(uu[e] & 0xffff);
            Kb[(k8 + 2 * e + 1) * 234 + nb] = (u16)(uu[e] >> 16);
        }
    }
    for (int g = tid; g < 1792; g += 256) {   // 64 dims x 28 pad cols
        int d = g / 28, nb = 196 + (g - d * 28);
        Kb[d * 234 + nb] = 0;
    }

    // ---- masked softmax over S rows; write P bf16 in place (pads -> 0)
    {
        int l16 = lane & 15, g4 = lane >> 4;
        #pragma unroll
        for (int it = 0; it < 4; it++) {
            int rr = w * 16 + it * 4 + g4;    // query row 0..63
            int i2 = ti + (rr >> 3), j2 = tj + (rr & 7);
            int alo = min(max(i2 - 3, 0), 25) - r0;
            int blo = min(max(j2 - 3, 0), 25) - c0;
            const _Float16* sp = (const _Float16*)&Sb[rr * 232];
            float vals[14];
            float mx = -1e30f;
            #pragma unroll
            for (int c = 0; c < 14; c++) {
                int col = l16 + c * 16;
                float v = -1e30f;
                if (col < 196) {
                    int ar = col / 14, ac = col - ar * 14;
                    if (ar >= alo && ar < alo + 7 && ac >= blo && ac < blo + 7)
                        v = (float)sp[col];
                }
                vals[c] = v; mx = fmaxf(mx, v);
            }
            #pragma unroll
            for (int d = 1; d < 16; d <<= 1) mx = fmaxf(mx, __shfl_xor(mx, d));
            float s = 0.f;
            #pragma unroll
            for (int c = 0; c < 14; c++) {
                float e = (vals[c] > -1e29f) ? expf(vals[c] - mx) : 0.f;
                vals[c] = e; s += e;
            }
            #pragma unroll
            for (int d = 1; d < 16; d <<= 1) s += __shfl_xor(s, d);
            float rs = __frcp_rn(s);
            u16* pp = &Sb[rr * 232];
            #pragma unroll
            for (int c = 0; c < 14; c++)
                pp[l16 + c * 16] = f2bf(vals[c] * rs);
        }
    }
    __syncthreads();

    // ---- O = P V  (wave w = query m-tile; 4 n-tiles of dims)
    f32x4 oacc[4];
    #pragma unroll
    for (int nt = 0; nt < 4; nt++) { f32x4 z = {0.f,0.f,0.f,0.f}; oacc[nt] = z; }
    #pragma unroll
    for (int ks = 0; ks < 7; ks++) {
        bf16x8 pa = *(const bf16x8*)&Sb[(w * 16 + m) * 232 + ks * 32 + quad * 8];
        #pragma unroll
        for (int nt = 0; nt < 4; nt++) {
            int ad = (nt * 16 + m) * 234 + ks * 32 + quad * 8;  // u16 idx, 4B-aligned
            union { u32 u[4]; bf16x8 v; } vb;
            vb.u[0] = *(const u32*)&Kb[ad];
            vb.u[1] = *(const u32*)&Kb[ad + 2];
            vb.u[2] = *(const u32*)&Kb[ad + 4];
            vb.u[3] = *(const u32*)&Kb[ad + 6];
            oacc[nt] = __builtin_amdgcn_mfma_f32_16x16x32_bf16(pa, vb.v, oacc[nt], 0, 0, 0);
        }
    }
    #pragma unroll
    for (int nt = 0; nt < 4; nt++) {
        #pragma unroll
        for (int reg = 0; reg < 4; reg++) {
            int rr = w * 16 + quad * 4 + reg;
            int tok = (ti + (rr >> 3)) * 32 + (tj + (rr & 7));
            ob[(size_t)(n * 1024 + tok) * 512 + h * 64 + nt * 16 + m] = f2bf(oacc[nt][reg]);
        }
    }
}

extern "C" void kernel_launch(void* const* d_in, const int* in_sizes, int n_in,
                              void* d_out, int out_size, void* d_ws, size_t ws_size,
                              hipStream_t stream)
{
    // Match inputs by unique element count (robust to ordering).
    const float *x = nullptr, *pos = nullptr, *cond = nullptr, *w_cond = nullptr,
                *w_qkv = nullptr, *scale = nullptr, *w_out = nullptr;
    for (int i = 0; i < n_in; i++) {
        switch (in_sizes[i]) {
            case 1048576: x      = (const float*)d_in[i]; break;  // 2*32*32*512
            case 2048:    pos    = (const float*)d_in[i]; break;  // 2*32*32*1
            case 1536:    cond   = (const float*)d_in[i]; break;  // 2*768
            case 393216:  w_cond = (const float*)d_in[i]; break;  // 512*768
            case 786432:  w_qkv  = (const float*)d_in[i]; break;  // 1536*512
            case 8:       scale  = (const float*)d_in[i]; break;  // 8
            case 262144:  w_out  = (const float*)d_in[i]; break;  // 512*512
            default: break;
        }
    }
    float* out = (float*)d_out;   // FLOAT32 output

    // ws: ns 4K | inv 8K | qkvb 6M | xn 2M | wqkvb 1.5M | woutb .5M | qp/kp/vp 6M | ob 2M
    char* ws = (char*)d_ws;
    float* ns    = (float*)ws;                          // [2][512]
    float* inv   = (float*)(ws + 4096);                 // [2048]
    u16*   qkvb  = (u16*)(ws + 12288);                  // [2048][1536] bf16
    u16*   xn    = (u16*)(ws + 12288 + 6291456);        // [2048][512]  bf16
    u16*   wqkvb = (u16*)(ws + 12288 + 8388608);        // [1536][512]  bf16
    u16*   woutb = (u16*)(ws + 12288 + 9961472);        // [512][512]   bf16
    u16*   qp    = (u16*)(ws + 12288 + 10485760);       // [2][8][1024][64] bf16
    u16*   kp    = (u16*)(ws + 12288 + 12582912);       // same
    u16*   vp    = (u16*)(ws + 12288 + 14680064);       // same
    u16*   ob    = (u16*)(ws + 12288 + 16777216);       // [2048][512]  bf16

    setup_kernel<<<768, 256, 0, stream>>>(cond, w_cond, x, ns, inv);
    convert_kernel<<<2048, 256, 0, stream>>>(x, ns, inv, w_qkv, w_out, xn, wqkvb, woutb);
    gemm_bt<true, false><<<dim3(32, 24), 256, 0, stream>>>(xn, wqkvb, nullptr, qkvb, nullptr, 1536, 512);
    rope_plane_kernel<<<12288, 256, 0, stream>>>(qkvb, pos, scale, qp, kp, vp);
    attn_mfma<<<256, 256, 0, stream>>>(qp, kp, vp, ob);
    gemm_bt<false, true><<<dim3(32, 8), 256, 0, stream>>>(ob, woutb, out, nullptr, x, 512, 512);
}

// Round 11
// 115.167 us; speedup vs baseline: 2.0143x; 1.0516x over previous
//
#include <hip/hip_runtime.h>

typedef unsigned short u16;
typedef unsigned int u32;
typedef __bf16 bf16x8 __attribute__((ext_vector_type(8)));
typedef float f32x4 __attribute__((ext_vector_type(4)));

__device__ __forceinline__ float bf2f(u16 v) {
    union { u32 u; float f; } c; c.u = ((u32)v) << 16; return c.f;
}
__device__ __forceinline__ u16 f2bf(float f) {
    union { float f; u32 u; } c; c.f = f;
    u32 u = c.u + 0x7fffu + ((c.u >> 16) & 1u);   // RNE
    return (u16)(u >> 16);
}

// ---------------- K1: fused cond_scale (blocks 0..255) + rms_inv (blocks 256..767)
__global__ __launch_bounds__(256) void setup_kernel(
    const float* __restrict__ cond, const float* __restrict__ w_cond,
    const float* __restrict__ x, float* __restrict__ ns, float* __restrict__ inv)
{
    int lane = threadIdx.x & 63;
    int b = blockIdx.x;
    if (b < 256) {
        int wid = b * 4 + (threadIdx.x >> 6); // 0..1023
        int n = wid >> 9, c = wid & 511;
        const float* cp = cond + n * 768;
        const float* wp = w_cond + (size_t)c * 768;
        float s = 0.f;
        #pragma unroll
        for (int j = 0; j < 12; j++)
            s += cp[lane + j * 64] * wp[lane + j * 64];
        #pragma unroll
        for (int d = 1; d < 64; d <<= 1) s += __shfl_xor(s, d);
        if (lane == 0) ns[wid] = s + 1.f;
    } else {
        int p = (b - 256) * 4 + (threadIdx.x >> 6); // 0..2047
        const float* xp = x + (size_t)p * 512;
        float s = 0.f;
        #pragma unroll
        for (int j = 0; j < 8; j++) { float v = xp[lane + j * 64]; s += v * v; }
        #pragma unroll
        for (int d = 1; d < 64; d <<= 1) s += __shfl_xor(s, d);
        if (lane == 0) inv[p] = rsqrtf(s * (1.f / 512.f) + 1e-6f);
    }
}

// ---------------- K2: bf16 conversions. blocks 0..1023: xn = rmsnorm(x)*ns (fused);
// blocks 1024..1791: w_qkv -> bf16 ; blocks 1792..2047: w_out -> bf16
__global__ __launch_bounds__(256) void convert_kernel(
    const float* __restrict__ x, const float* __restrict__ ns, const float* __restrict__ inv,
    const float* __restrict__ w_qkv, const float* __restrict__ w_out,
    u16* __restrict__ xn, u16* __restrict__ wqkvb, u16* __restrict__ woutb)
{
    int b = blockIdx.x;
    const float* src; u16* dst; size_t i4;
    bool rms = false;
    if (b < 1024)      { src = x;     dst = xn;    i4 = (size_t)(b)        * 1024 + threadIdx.x * 4; rms = true; }
    else if (b < 1792) { src = w_qkv; dst = wqkvb; i4 = (size_t)(b - 1024) * 1024 + threadIdx.x * 4; }
    else               { src = w_out; dst = woutb; i4 = (size_t)(b - 1792) * 1024 + threadIdx.x * 4; }
    float4 v = *(const float4*)(src + i4);
    if (rms) {
        int p = (int)(i4 >> 9), c = (int)(i4 & 511);
        float iv = inv[p];
        float4 nv = *(const float4*)(ns + (p >> 10) * 512 + c);
        v.x *= nv.x * iv; v.y *= nv.y * iv; v.z *= nv.z * iv; v.w *= nv.w * iv;
    }
    ushort4 o; o.x = f2bf(v.x); o.y = f2bf(v.y); o.z = f2bf(v.z); o.w = f2bf(v.w);
    *(ushort4*)(dst + i4) = o;
}

// ---------------- K3: qkv GEMM with fused q/k norm + RoPE epilogue.
// C = xn @ wqkvb^T over 64x64 tiles; block (bx,by): rows bx*64 tokens, cols = one
// (qk,head) slice (by: 0..7 q / 8..15 k / 16..23 v). Writes head-major planes.
// A-frag: m=lane&15, k=(lane>>4)*8+j ; C/D: col=lane&15, row=(lane>>4)*4+reg [m89/m91]
// RoPE pair (d, d+16), d<16: ci=0/ci=1 of wn==0 wave -> register-local rotation.
__global__ __launch_bounds__(256) void gemm_qkv(
    const u16* __restrict__ A, const u16* __restrict__ B,
    const float* __restrict__ pos, const float* __restrict__ scale,
    u16* __restrict__ qp, u16* __restrict__ kp, u16* __restrict__ vp)
{
    __shared__ __align__(16) u16 As[64][40];
    __shared__ __align__(16) u16 Bs[64][40];
    int tid = threadIdx.x;
    int lane = tid & 63;
    int w = tid >> 6;
    int wm = w >> 1, wn = w & 1;
    int bm = blockIdx.x * 64, bn = blockIdx.y * 64;
    int qk = blockIdx.y >> 3, h = blockIdx.y & 7;
    int lrow = tid >> 2, lc8 = (tid & 3) * 8;

    f32x4 zero = {0.f, 0.f, 0.f, 0.f};
    f32x4 acc[2][2];
    acc[0][0] = zero; acc[0][1] = zero; acc[1][0] = zero; acc[1][1] = zero;

    const u16* Ap = A + (size_t)(bm + lrow) * 512 + lc8;
    const u16* Bp = B + (size_t)(bn + lrow) * 512 + lc8;
    int m = lane & 15, quad = lane >> 4, kq = quad * 8;

    for (int k0 = 0; k0 < 512; k0 += 32) {
        *(uint4*)&As[lrow][lc8] = *(const uint4*)(Ap + k0);
        *(uint4*)&Bs[lrow][lc8] = *(const uint4*)(Bp + k0);
        __syncthreads();
        #pragma unroll
        for (int ri = 0; ri < 2; ri++) {
            bf16x8 af = *(const bf16x8*)&As[wm * 32 + ri * 16 + m][kq];
            #pragma unroll
            for (int ci = 0; ci < 2; ci++) {
                bf16x8 bfr = *(const bf16x8*)&Bs[wn * 32 + ci * 16 + m][kq];
                acc[ri][ci] = __builtin_amdgcn_mfma_f32_16x16x32_bf16(af, bfr, acc[ri][ci], 0, 0, 0);
            }
        }
        __syncthreads();
    }

    // ---- epilogue: head-norm (sum over 64 cols) + RoPE for q/k; passthrough v
    float invn[2][4];
    if (qk < 2) {
        float* red = (float*)As;   // [64][2] partials, reuse LDS
        #pragma unroll
        for (int ri = 0; ri < 2; ri++)
        #pragma unroll
        for (int reg = 0; reg < 4; reg++) {
            float pa = acc[ri][0][reg] * acc[ri][0][reg]
                     + acc[ri][1][reg] * acc[ri][1][reg];
            #pragma unroll
            for (int d = 1; d < 16; d <<= 1) pa += __shfl_xor(pa, d);
            if (m == 0) red[(wm * 32 + ri * 16 + quad * 4 + reg) * 2 + wn] = pa;
        }
        __syncthreads();
        float sq = sqrtf(scale[h]);
        #pragma unroll
        for (int ri = 0; ri < 2; ri++)
        #pragma unroll
        for (int reg = 0; reg < 4; reg++) {
            int rl = wm * 32 + ri * 16 + quad * 4 + reg;
            invn[ri][reg] = sq * rsqrtf(red[rl * 2] + red[rl * 2 + 1] + 1e-6f);
        }
    }
    u16* plane = (qk == 0) ? qp : (qk == 1) ? kp : vp;
    // freqs[h][t] = pi * 10^((t*8+h)/128), t = m
    float fr = 3.14159265358979323846f * expf((float)(m * 8 + h) * (2.302585092994046f / 128.f));
    #pragma unroll
    for (int ri = 0; ri < 2; ri++)
    #pragma unroll
    for (int reg = 0; reg < 4; reg++) {
        int rl = wm * 32 + ri * 16 + quad * 4 + reg;
        int p = bm + rl;
        size_t basep = ((size_t)((p >> 10) * 8 + h) * 1024 + (p & 1023)) * 64;
        float v0 = acc[ri][0][reg], v1 = acc[ri][1][reg];
        if (qk < 2) {
            float ivn = invn[ri][reg];
            v0 *= ivn; v1 *= ivn;
            if (wn == 0) {   // dims 0..31: rotate (d, d+16)
                float th = pos[p] * fr;
                float cs = cosf(th), sn = sinf(th);
                float o0 = v0 * cs - v1 * sn;
                float o1 = v1 * cs + v0 * sn;
                v0 = o0; v1 = o1;
            }
        }
        plane[basep + wn * 32 + m]      = f2bf(v0);
        plane[basep + wn * 32 + 16 + m] = f2bf(v1);
    }
}

// ---------------- MFMA GEMM (out proj): C[M][N] fp32 = A @ B^T + skip
__global__ __launch_bounds__(256) void gemm_out(
    const u16* __restrict__ A, const u16* __restrict__ B,
    float* __restrict__ C, const float* __restrict__ skip, int N, int K)
{
    __shared__ __align__(16) u16 As[64][40];
    __shared__ __align__(16) u16 Bs[64][40];
    int tid = threadIdx.x;
    int lane = tid & 63;
    int w = tid >> 6;
    int wm = w >> 1, wn = w & 1;
    int bm = blockIdx.x * 64, bn = blockIdx.y * 64;
    int lrow = tid >> 2, lc8 = (tid & 3) * 8;

    f32x4 zero = {0.f, 0.f, 0.f, 0.f};
    f32x4 acc[2][2];
    acc[0][0] = zero; acc[0][1] = zero; acc[1][0] = zero; acc[1][1] = zero;

    const u16* Ap = A + (size_t)(bm + lrow) * K + lc8;
    const u16* Bp = B + (size_t)(bn + lrow) * K + lc8;
    int r = lane & 15, kq = (lane >> 4) * 8;

    for (int k0 = 0; k0 < K; k0 += 32) {
        *(uint4*)&As[lrow][lc8] = *(const uint4*)(Ap + k0);
        *(uint4*)&Bs[lrow][lc8] = *(const uint4*)(Bp + k0);
        __syncthreads();
        #pragma unroll
        for (int ri = 0; ri < 2; ri++) {
            bf16x8 af = *(const bf16x8*)&As[wm * 32 + ri * 16 + r][kq];
            #pragma unroll
            for (int ci = 0; ci < 2; ci++) {
                bf16x8 bfr = *(const bf16x8*)&Bs[wn * 32 + ci * 16 + r][kq];
                acc[ri][ci] = __builtin_amdgcn_mfma_f32_16x16x32_bf16(af, bfr, acc[ri][ci], 0, 0, 0);
            }
        }
        __syncthreads();
    }

    #pragma unroll
    for (int ri = 0; ri < 2; ri++)
    #pragma unroll
    for (int ci = 0; ci < 2; ci++) {
        int col = bn + wn * 32 + ci * 16 + (lane & 15);
        int row0 = bm + wm * 32 + ri * 16 + (lane >> 4) * 4;
        #pragma unroll
        for (int reg = 0; reg < 4; reg++) {
            size_t idx = (size_t)(row0 + reg) * N + col;
            C[idx] = acc[ri][ci][reg] + skip[idx];
        }
    }
}

// ---------------- K5: MFMA neighborhood attention.
// One block per (n, h, 8x8 query tile). Union of neighborhoods = 14x14 = 196 keys.
__global__ __launch_bounds__(256) void attn_mfma(
    const u16* __restrict__ qp, const u16* __restrict__ kp, const u16* __restrict__ vp,
    u16* __restrict__ ob)
{
    __shared__ __align__(16) u16 Kb[208 * 72];   // K:[nb][64] stride 72; reused as Vt:[64][224] stride 234
    __shared__ __align__(16) u16 Sb[64 * 232];   // S fp16 then P bf16, row stride 232

    int tid = threadIdx.x, lane = tid & 63, w = tid >> 6;
    int bx = blockIdx.x;
    int n = bx >> 7, h = (bx >> 4) & 7, t = bx & 15;
    int ti = (t >> 2) * 8, tj = (t & 3) * 8;
    int r0 = min(max(ti - 3, 0), 18), c0 = min(max(tj - 3, 0), 18);
    const u16* qpl = qp + ((size_t)(n * 8 + h) << 16);
    const u16* kpl = kp + ((size_t)(n * 8 + h) << 16);
    const u16* vpl = vp + ((size_t)(n * 8 + h) << 16);

    for (int g = tid; g < 1568; g += 256) {
        int nb = g >> 3, k8 = (g & 7) << 3;
        int ar = nb / 14, ac = nb - ar * 14;
        *(uint4*)&Kb[nb * 72 + k8] =
            *(const uint4*)&kpl[(size_t)((r0 + ar) * 32 + c0 + ac) * 64 + k8];
    }
    __syncthreads();

    int m = lane & 15, quad = lane >> 4;
    {
        int r = w * 16 + m;
        int tok = (ti + (r >> 3)) * 32 + (tj + (r & 7));
        bf16x8 qf0 = *(const bf16x8*)&qpl[(size_t)tok * 64 + quad * 8];
        bf16x8 qf1 = *(const bf16x8*)&qpl[(size_t)tok * 64 + 32 + quad * 8];
        _Float16* sp = (_Float16*)Sb;
        #pragma unroll
        for (int nt = 0; nt < 13; nt++) {
            f32x4 acc = {0.f, 0.f, 0.f, 0.f};
            bf16x8 b0 = *(const bf16x8*)&Kb[(nt * 16 + m) * 72 + quad * 8];
            bf16x8 b1 = *(const bf16x8*)&Kb[(nt * 16 + m) * 72 + 32 + quad * 8];
            acc = __builtin_amdgcn_mfma_f32_16x16x32_bf16(qf0, b0, acc, 0, 0, 0);
            acc = __builtin_amdgcn_mfma_f32_16x16x32_bf16(qf1, b1, acc, 0, 0, 0);
            #pragma unroll
            for (int reg = 0; reg < 4; reg++)
                sp[(w * 16 + quad * 4 + reg) * 232 + nt * 16 + m] = (_Float16)acc[reg];
        }
    }
    __syncthreads();

    for (int g = tid; g < 1568; g += 256) {
        int nb = g >> 3, k8 = (g & 7) << 3;
        int ar = nb / 14, ac = nb - ar * 14;
        uint4 v4 = *(const uint4*)&vpl[(size_t)((r0 + ar) * 32 + c0 + ac) * 64 + k8];
        u32 uu[4] = {v4.x, v4.y, v4.z, v4.w};
        #pragma unroll
        for (int e = 0; e < 4; e++) {
            Kb[(k8 + 2 * e) * 234 + nb]     = (u16)(uu[e] & 0xffff);
            Kb[(k8 + 2 * e + 1) * 234 + nb] = (u16)(uu[e] >> 16);
        }
    }
    for (int g = tid; g < 1792; g += 256) {
        int d = g / 28, nb = 196 + (g - d * 28);
        Kb[d * 234 + nb] = 0;
    }

    {
        int l16 = lane & 15, g4 = lane >> 4;
        #pragma unroll
        for (int it = 0; it < 4; it++) {
            int rr = w * 16 + it * 4 + g4;
            int i2 = ti + (rr >> 3), j2 = tj + (rr & 7);
            int alo = min(max(i2 - 3, 0), 25) - r0;
            int blo = min(max(j2 - 3, 0), 25) - c0;
            const _Float16* sp = (const _Float16*)&Sb[rr * 232];
            float vals[14];
            float mx = -1e30f;
            #pragma unroll
            for (int c = 0; c < 14; c++) {
                int col = l16 + c * 16;
                float v = -1e30f;
                if (col < 196) {
                    int ar = col / 14, ac = col - ar * 14;
                    if (ar >= alo && ar < alo + 7 && ac >= blo && ac < blo + 7)
                        v = (float)sp[col];
                }
                vals[c] = v; mx = fmaxf(mx, v);
            }
            #pragma unroll
            for (int d = 1; d < 16; d <<= 1) mx = fmaxf(mx, __shfl_xor(mx, d));
            float s = 0.f;
            #pragma unroll
            for (int c = 0; c < 14; c++) {
                float e = (vals[c] > -1e29f) ? expf(vals[c] - mx) : 0.f;
                vals[c] = e; s += e;
            }
            #pragma unroll
            for (int d = 1; d < 16; d <<= 1) s += __shfl_xor(s, d);
            float rs = __frcp_rn(s);
            u16* pp = &Sb[rr * 232];
            #pragma unroll
            for (int c = 0; c < 14; c++)
                pp[l16 + c * 16] = f2bf(vals[c] * rs);
        }
    }
    __syncthreads();

    f32x4 oacc[4];
    #pragma unroll
    for (int nt = 0; nt < 4; nt++) { f32x4 z = {0.f,0.f,0.f,0.f}; oacc[nt] = z; }
    #pragma unroll
    for (int ks = 0; ks < 7; ks++) {
        bf16x8 pa = *(const bf16x8*)&Sb[(w * 16 + m) * 232 + ks * 32 + quad * 8];
        #pragma unroll
        for (int nt = 0; nt < 4; nt++) {
            int ad = (nt * 16 + m) * 234 + ks * 32 + quad * 8;
            union { u32 u[4]; bf16x8 v; } vb;
            vb.u[0] = *(const u32*)&Kb[ad];
            vb.u[1] = *(const u32*)&Kb[ad + 2];
            vb.u[2] = *(const u32*)&Kb[ad + 4];
            vb.u[3] = *(const u32*)&Kb[ad + 6];
            oacc[nt] = __builtin_amdgcn_mfma_f32_16x16x32_bf16(pa, vb.v, oacc[nt], 0, 0, 0);
        }
    }
    #pragma unroll
    for (int nt = 0; nt < 4; nt++) {
        #pragma unroll
        for (int reg = 0; reg < 4; reg++) {
            int rr = w * 16 + quad * 4 + reg;
            int tok = (ti + (rr >> 3)) * 32 + (tj + (rr & 7));
            ob[(size_t)(n * 1024 + tok) * 512 + h * 64 + nt * 16 + m] = f2bf(oacc[nt][reg]);
        }
    }
}

extern "C" void kernel_launch(void* const* d_in, const int* in_sizes, int n_in,
                              void* d_out, int out_size, void* d_ws, size_t ws_size,
                              hipStream_t stream)
{
    // Match inputs by unique element count (robust to ordering).
    const float *x = nullptr, *pos = nullptr, *cond = nullptr, *w_cond = nullptr,
                *w_qkv = nullptr, *scale = nullptr, *w_out = nullptr;
    for (int i = 0; i < n_in; i++) {
        switch (in_sizes[i]) {
            case 1048576: x      = (const float*)d_in[i]; break;  // 2*32*32*512
            case 2048:    pos    = (const float*)d_in[i]; break;  // 2*32*32*1
            case 1536:    cond   = (const float*)d_in[i]; break;  // 2*768
            case 393216:  w_cond = (const float*)d_in[i]; break;  // 512*768
            case 786432:  w_qkv  = (const float*)d_in[i]; break;  // 1536*512
            case 8:       scale  = (const float*)d_in[i]; break;  // 8
            case 262144:  w_out  = (const float*)d_in[i]; break;  // 512*512
            default: break;
        }
    }
    float* out = (float*)d_out;   // FLOAT32 output

    // ws: ns 4K | inv 8K | xn 2M | wqkvb 1.5M | woutb .5M | qp/kp/vp 2M each | ob 2M
    char* ws = (char*)d_ws;
    float* ns    = (float*)ws;                          // [2][512]
    float* inv   = (float*)(ws + 4096);                 // [2048]
    u16*   xn    = (u16*)(ws + 12288);                  // [2048][512]  bf16
    u16*   wqkvb = (u16*)(ws + 12288 + 2097152);        // [1536][512]  bf16
    u16*   woutb = (u16*)(ws + 12288 + 3670016);        // [512][512]   bf16
    u16*   qp    = (u16*)(ws + 12288 + 4194304);        // [2][8][1024][64] bf16
    u16*   kp    = (u16*)(ws + 12288 + 6291456);        // same
    u16*   vp    = (u16*)(ws + 12288 + 8388608);        // same
    u16*   ob    = (u16*)(ws + 12288 + 10485760);       // [2048][512]  bf16

    setup_kernel<<<768, 256, 0, stream>>>(cond, w_cond, x, ns, inv);
    convert_kernel<<<2048, 256, 0, stream>>>(x, ns, inv, w_qkv, w_out, xn, wqkvb, woutb);
    gemm_qkv<<<dim3(32, 24), 256, 0, stream>>>(xn, wqkvb, pos, scale, qp, kp, vp);
    attn_mfma<<<256, 256, 0, stream>>>(qp, kp, vp, ob);
    gemm_out<<<dim3(32, 8), 256, 0, stream>>>(ob, woutb, out, x, 512, 512);
}